// Round 8
// baseline (330.970 us; speedup 1.0000x reference)
//
#include <hip/hip_runtime.h>
#include <hip/hip_fp16.h>

#define N_NODES   100000
#define N_EDGES   3200000
#define F_IN      256
#define HID       16
#define NCLS      40

#define CHUNK     8192
#define NBLK      ((N_EDGES + CHUNK - 1) / CHUNK)    // 391 edge chunks
#define B2SHIFT   9                                  // 512 nodes per coarse bucket
#define NB2       ((N_NODES + 511) >> B2SHIFT)       // 196 buckets
#define BCAP      17408                              // LDS edge cache in build (mean 16384, +8 sigma)

#define COMP(v, kk) ((kk) == 0 ? (v).x : (kk) == 1 ? (v).y : (kk) == 2 ? (v).z : (v).w)

// ---- K1: per-chunk coarse histogram + layer-1 GEMM (scalar-path weights) ----
// Weights are wave-uniform -> read straight from global W1 (s_load via const cache,
// FMA takes the SGPR operand). No LDS in the gemm at all; LDS pipe freed.
// Grid 391 covers all 256 CUs (~6 waves/CU); unroll-4 x-stream for ~4KB in flight/wave.
// y1h = raw fp16(x@W1); dinv scaling applied later in k3 (when dinv exists).
__global__ __launch_bounds__(256) void k1_hist_gemm(const int* __restrict__ ei,
                                                    const float* __restrict__ x,
                                                    const float* __restrict__ W1,
                                                    int* __restrict__ hist_blk,
                                                    __half* __restrict__ y1h) {
    __shared__ int h[NB2];
    int blk = blockIdx.x, t = threadIdx.x;

    // ---- hist phase ----
    for (int i = t; i < NB2; i += 256) h[i] = 0;
    __syncthreads();
    int e0 = blk * CHUNK;
    int eN = min(CHUNK, N_EDGES - e0);               // always %4 == 0 (last = 5120)
    const int4* d4 = (const int4*)(ei + N_EDGES + e0);
    for (int i = t; i < (eN >> 2); i += 256) {
        int4 d = d4[i];
        atomicAdd(&h[d.x >> B2SHIFT], 1);
        atomicAdd(&h[d.y >> B2SHIFT], 1);
        atomicAdd(&h[d.z >> B2SHIFT], 1);
        atomicAdd(&h[d.w >> B2SHIFT], 1);
    }
    __syncthreads();
    for (int i = t; i < NB2; i += 256) hist_blk[i * NBLK + blk] = h[i];  // bucket-major

    // ---- gemm phase: 1 node/thread, scalar weight loads, deep x prefetch ----
    int n = blk * 256 + t;                           // 391*256 = 100096 >= N_NODES
    if (n >= N_NODES) return;

    const float4* xr = (const float4*)(x + (size_t)n * F_IN);
    float acc[HID];
    #pragma unroll
    for (int j = 0; j < HID; j++) acc[j] = 0.f;

    #pragma unroll 4
    for (int k4 = 0; k4 < F_IN / 4; k4++) {
        float4 xv = xr[k4];
        #pragma unroll
        for (int kk = 0; kk < 4; kk++) {
            const float xs = COMP(xv, kk);
            const float* w = W1 + (k4 * 4 + kk) * HID;   // wave-uniform -> s_load
            #pragma unroll
            for (int hh = 0; hh < HID; hh++) acc[hh] += xs * w[hh];
        }
    }
    __half2 hp[8];
    #pragma unroll
    for (int j = 0; j < 8; j++)
        hp[j] = __float22half2_rn(make_float2(acc[2 * j], acc[2 * j + 1]));
    float4* o = (float4*)(y1h + (size_t)n * HID);
    o[0] = ((float4*)hp)[0];
    o[1] = ((float4*)hp)[1];
}

// ---- K2: scatter edges into disjoint sub-ranges; per-bucket prefix recomputed in-block ----
// pack: (dst & 511) << 17 | src   (src < 2^17)
__global__ __launch_bounds__(512) void k2_bin(const int* __restrict__ ei,
                                              const int* __restrict__ hist_blk,
                                              int* __restrict__ buf) {
    __shared__ int cur[NB2];
    __shared__ int sc[256];
    int blk = blockIdx.x, t = threadIdx.x;
    int pre = 0, tot = 0;
    if (t < NB2) {
        const int* row = hist_blk + t * NBLK;
        for (int k = 0; k < NBLK; k++) {
            int v = row[k];
            pre += (k < blk) ? v : 0;
            tot += v;
        }
    }
    if (t < 256) sc[t] = tot;
    __syncthreads();
    for (int off = 1; off < 256; off <<= 1) {
        int u = 0;
        if (t < 256 && t >= off) u = sc[t - off];
        __syncthreads();
        if (t < 256) sc[t] += u;
        __syncthreads();
    }
    if (t < NB2) cur[t] = (sc[t] - tot) + pre;       // bucket_base + this block's prefix
    __syncthreads();

    int e0 = blk * CHUNK;
    int eN = min(CHUNK, N_EDGES - e0);               // always %4 == 0
    const int4* s4 = (const int4*)(ei + e0);
    const int4* d4 = (const int4*)(ei + N_EDGES + e0);
    for (int i = t; i < (eN >> 2); i += 512) {
        int4 d = d4[i], s = s4[i];
        int p0 = atomicAdd(&cur[d.x >> B2SHIFT], 1); buf[p0] = ((d.x & 511) << 17) | s.x;
        int p1 = atomicAdd(&cur[d.y >> B2SHIFT], 1); buf[p1] = ((d.y & 511) << 17) | s.y;
        int p2 = atomicAdd(&cur[d.z >> B2SHIFT], 1); buf[p2] = ((d.z & 511) << 17) | s.z;
        int p3 = atomicAdd(&cur[d.w >> B2SHIFT], 1); buf[p3] = ((d.w & 511) << 17) | s.w;
    }
}

// ---- K3: per-bucket fine build -> rowptr, dinv, csr_src; ALSO scales y1h row by dinv ----
// (fusing the y1h *= dinv[n] rescale here keeps gather1's edge loop free of dinv[src] loads)
__global__ __launch_bounds__(512) void k3_build(const int* __restrict__ buf,
                                               const int* __restrict__ hist_blk,
                                               int* __restrict__ rowptr,
                                               float* __restrict__ dinv,
                                               int* __restrict__ csr_src,
                                               __half* __restrict__ y1h) {
    __shared__ int lbuf[BCAP];
    __shared__ int hist[512], offs[512], cur[512];
    __shared__ int sc[256];
    __shared__ int s_base, s_cnt;
    int b = blockIdx.x, t = threadIdx.x;

    int tot = 0;
    if (t < NB2) {
        const int* row = hist_blk + t * NBLK;
        for (int k = 0; k < NBLK; k++) tot += row[k];
    }
    if (t < 256) sc[t] = tot;
    hist[t] = 0;
    __syncthreads();
    for (int off = 1; off < 256; off <<= 1) {
        int u = 0;
        if (t < 256 && t >= off) u = sc[t - off];
        __syncthreads();
        if (t < 256) sc[t] += u;
        __syncthreads();
    }
    if (t == b) { s_base = sc[b] - tot; s_cnt = tot; }
    __syncthreads();
    int base = s_base, cnt = s_cnt;

    for (int i = t; i < cnt; i += 512) {
        int v = buf[base + i];
        if (i < BCAP) lbuf[i] = v;
        atomicAdd(&hist[v >> 17], 1);
    }
    __syncthreads();
    int v = hist[t];
    offs[t] = v;
    __syncthreads();
    for (int off = 1; off < 512; off <<= 1) {
        int u = (t >= off) ? offs[t - off] : 0;
        __syncthreads();
        offs[t] += u;
        __syncthreads();
    }
    int ex = offs[t] - v;   // exclusive scan
    int n = (b << B2SHIFT) + t;
    if (n < N_NODES) {
        rowptr[n] = base + ex;
        float dv = rsqrtf((float)(v + 1));  // +1 self-loop
        dinv[n] = dv;
        // in-place rescale of this node's y1h row (row owned exclusively by this thread)
        float4* yr = (float4*)(y1h + (size_t)n * HID);
        float4 a = yr[0], bq = yr[1];
        __half2* ah = (__half2*)&a;
        __half2* bh = (__half2*)&bq;
        #pragma unroll
        for (int j = 0; j < 4; j++) {
            float2 fa = __half22float2(ah[j]);
            float2 fb = __half22float2(bh[j]);
            ah[j] = __float22half2_rn(make_float2(fa.x * dv, fa.y * dv));
            bh[j] = __float22half2_rn(make_float2(fb.x * dv, fb.y * dv));
        }
        yr[0] = a;
        yr[1] = bq;
    }
    if (b == 0 && t == 0) rowptr[N_NODES] = N_EDGES;
    cur[t] = ex;
    __syncthreads();
    for (int i = t; i < cnt; i += 512) {
        int p = (i < BCAP) ? lbuf[i] : buf[base + i];
        int pos = atomicAdd(&cur[p >> 17], 1);        // LDS atomic
        csr_src[base + pos] = p & 0x1FFFF;
    }
}

// ---- helper: accumulate one fp16 row (16 halfs as 2 float4) into acc[16] ----
__device__ __forceinline__ void acc_row(const float4* __restrict__ tab, int s, float* acc) {
    float4 v0 = tab[(size_t)s * 2 + 0];
    float4 v1 = tab[(size_t)s * 2 + 1];
    const __half2* a0 = (const __half2*)&v0;
    const __half2* a1 = (const __half2*)&v1;
    #pragma unroll
    for (int j = 0; j < 4; j++) {
        float2 f0 = __half22float2(a0[j]);
        float2 f1 = __half22float2(a1[j]);
        acc[2 * j]         += f0.x;
        acc[2 * j + 1]     += f0.y;
        acc[8 + 2 * j]     += f1.x;
        acc[8 + 2 * j + 1] += f1.y;
    }
}

// ---- helper: two fp16 rows with all 4 row-loads in flight ----
__device__ __forceinline__ void acc_row2(const float4* __restrict__ tab, int s0, int s1, float* acc) {
    float4 v0 = tab[(size_t)s0 * 2 + 0];
    float4 v1 = tab[(size_t)s0 * 2 + 1];
    float4 v2 = tab[(size_t)s1 * 2 + 0];
    float4 v3 = tab[(size_t)s1 * 2 + 1];
    const __half2* a0 = (const __half2*)&v0;
    const __half2* a1 = (const __half2*)&v1;
    const __half2* b0 = (const __half2*)&v2;
    const __half2* b1 = (const __half2*)&v3;
    #pragma unroll
    for (int j = 0; j < 4; j++) {
        float2 f0 = __half22float2(a0[j]);
        float2 f1 = __half22float2(a1[j]);
        float2 g0 = __half22float2(b0[j]);
        float2 g1 = __half22float2(b1[j]);
        acc[2 * j]         += f0.x + g0.x;
        acc[2 * j + 1]     += f0.y + g0.y;
        acc[8 + 2 * j]     += f1.x + g1.x;
        acc[8 + 2 * j + 1] += f1.y + g1.y;
    }
}

// ---- gather 1 (4 lanes/node): zh = fp16( dinv_n * relu(dinv_n * agg + b1) ) ----
// y1h rows pre-scaled by dinv[src] in k3, so the edge loop is pure row-sums.
__global__ __launch_bounds__(256) void gather1_kernel(const int* __restrict__ rowptr,
                                                      const int* __restrict__ csr_src,
                                                      const __half* __restrict__ y1h,
                                                      const float* __restrict__ b1,
                                                      const float* __restrict__ dinv,
                                                      __half* __restrict__ zh) {
    int n   = blockIdx.x * 64 + (threadIdx.x >> 2);
    int sub = threadIdx.x & 3;
    if (n >= N_NODES) return;
    const float4* tab = (const float4*)y1h;
    int beg = rowptr[n], end = rowptr[n + 1];
    float acc[16];
    #pragma unroll
    for (int i = 0; i < 16; i++) acc[i] = 0.f;
    if (sub == 0) acc_row(tab, n, acc);               // self-loop (row pre-scaled by dinv_n)
    int e = beg + sub;
    for (; e + 4 < end; e += 8)
        acc_row2(tab, csr_src[e], csr_src[e + 4], acc);
    if (e < end) acc_row(tab, csr_src[e], acc);
    #pragma unroll
    for (int m = 1; m < 4; m <<= 1) {
        #pragma unroll
        for (int i = 0; i < 16; i++) acc[i] += __shfl_xor(acc[i], m, 4);
    }
    if (sub < 2) {
        float dvn = dinv[n];
        const float4* b1q = (const float4*)b1;
        float4 ba = b1q[sub * 2], bb = b1q[sub * 2 + 1];
        float bv[8] = {ba.x, ba.y, ba.z, ba.w, bb.x, bb.y, bb.z, bb.w};
        __half2 outp[4];
        #pragma unroll
        for (int j = 0; j < 4; j++) {
            float2 r;
            r.x = fmaxf(dvn * acc[sub * 8 + 2 * j]     + bv[2 * j],     0.f) * dvn;
            r.y = fmaxf(dvn * acc[sub * 8 + 2 * j + 1] + bv[2 * j + 1], 0.f) * dvn;
            outp[j] = __float22half2_rn(r);
        }
        *(float4*)(zh + (size_t)n * HID + sub * 8) = *(float4*)outp;
    }
}

// ---- gather 2 + output GEMM fused: out[n,c] = dinv_n*(agg@W2)[c] + b2[c] ----
__global__ __launch_bounds__(256) void gather2_kernel(const int* __restrict__ rowptr,
                                                      const int* __restrict__ csr_src,
                                                      const __half* __restrict__ zh,
                                                      const float* __restrict__ W2,
                                                      const float* __restrict__ b2,
                                                      const float* __restrict__ dinv,
                                                      float* __restrict__ out) {
    __shared__ float W2s[HID * NCLS];   // 640 floats
    __shared__ float b2s[NCLS];
    int t = threadIdx.x;
    for (int i = t; i < HID * NCLS; i += 256) W2s[i] = W2[i];
    if (t < NCLS) b2s[t] = b2[t];
    __syncthreads();

    int n   = blockIdx.x * 64 + (t >> 2);
    int sub = t & 3;
    if (n >= N_NODES) return;
    const float4* tab = (const float4*)zh;
    int beg = rowptr[n], end = rowptr[n + 1];
    float acc[16];
    #pragma unroll
    for (int i = 0; i < 16; i++) acc[i] = 0.f;
    if (sub == 0) acc_row(tab, n, acc);               // self-loop (zh pre-scaled)
    int e = beg + sub;
    for (; e + 4 < end; e += 8)
        acc_row2(tab, csr_src[e], csr_src[e + 4], acc);
    if (e < end) acc_row(tab, csr_src[e], acc);
    #pragma unroll
    for (int m = 1; m < 4; m <<= 1) {
        #pragma unroll
        for (int i = 0; i < 16; i++) acc[i] += __shfl_xor(acc[i], m, 4);
    }
    // each lane computes 10 contiguous classes
    float dv = dinv[n];
    int c0 = sub * 10;
    float o[10];
    #pragma unroll
    for (int j = 0; j < 10; j++) o[j] = 0.f;
    #pragma unroll
    for (int h = 0; h < HID; h++) {
        float a = acc[h];
        const float* w = &W2s[h * NCLS + c0];
        #pragma unroll
        for (int j = 0; j < 10; j++) o[j] += a * w[j];
    }
    float* op = out + (size_t)n * NCLS + c0;
    #pragma unroll
    for (int j = 0; j < 5; j++) {
        float2 r = make_float2(dv * o[2 * j]     + b2s[c0 + 2 * j],
                               dv * o[2 * j + 1] + b2s[c0 + 2 * j + 1]);
        *(float2*)(op + 2 * j) = r;
    }
}

extern "C" void kernel_launch(void* const* d_in, const int* in_sizes, int n_in,
                              void* d_out, int out_size, void* d_ws, size_t ws_size,
                              hipStream_t stream) {
    const float* x   = (const float*)d_in[0];
    const int*   ei  = (const int*)  d_in[1];   // [2, E] int32
    const float* W1  = (const float*)d_in[2];
    const float* b1  = (const float*)d_in[3];
    const float* W2  = (const float*)d_in[4];
    const float* b2  = (const float*)d_in[5];
    float* out = (float*)d_out;

    char* ws = (char*)d_ws;
    size_t off = 0;
    int*   hist_blk = (int*)(ws + off); off += (size_t)NB2 * NBLK * 4;       // 307 KB
    off = (off + 15) & ~(size_t)15;
    int*    rowptr  = (int*)   (ws + off); off += (size_t)(N_NODES + 1) * 4;
    off = (off + 15) & ~(size_t)15;
    float*  dinv    = (float*) (ws + off); off += (size_t)N_NODES * 4;
    int*    csr_src = (int*)   (ws + off); off += (size_t)N_EDGES * 4;          // 12.8 MB
    int*    buf     = (int*)   (ws + off); off += (size_t)N_EDGES * 4;          // 12.8 MB
    __half* y1h     = (__half*)(ws + off); off += (size_t)N_NODES * HID * 2;    //  3.2 MB
    __half* zh      = (__half*)(ws + off); off += (size_t)N_NODES * HID * 2;    //  3.2 MB

    k1_hist_gemm <<<NBLK, 256, 0, stream>>>(ei, x, W1, hist_blk, y1h);
    k2_bin       <<<NBLK, 512, 0, stream>>>(ei, hist_blk, buf);
    k3_build     <<<NB2, 512, 0, stream>>>(buf, hist_blk, rowptr, dinv, csr_src, y1h);
    gather1_kernel<<<(N_NODES + 63) / 64, 256, 0, stream>>>(rowptr, csr_src, y1h, b1, dinv, zh);
    gather2_kernel<<<(N_NODES + 63) / 64, 256, 0, stream>>>(rowptr, csr_src, zh, W2, b2, dinv, out);
}

// Round 9
// 317.405 us; speedup vs baseline: 1.0427x; 1.0427x over previous
//
#include <hip/hip_runtime.h>
#include <hip/hip_fp16.h>

#define N_NODES   100000
#define N_EDGES   3200000
#define F_IN      256
#define HID       16
#define NCLS      40

#define CHUNK     16384
#define NBLK      ((N_EDGES + CHUNK - 1) / CHUNK)    // 196 edge chunks
#define B2SHIFT   9                                  // 512 nodes per coarse bucket
#define NB2       ((N_NODES + 511) >> B2SHIFT)       // 196 buckets
#define BCAP      17408                              // LDS edge cache in build (mean 16384, +8 sigma)
#define G1BLKS    ((N_NODES + 63) / 64)              // 1563 blocks for split-K gemm

#define COMP(v, kk) ((kk) == 0 ? (v).x : (kk) == 1 ? (v).y : (kk) == 2 ? (v).z : (v).w)

// ---- K1: per-chunk coarse histogram (first 196 blocks) + split-K layer-1 GEMM ----
// Occupancy fix: 64 nodes/block x 4 waves, each wave owns one K-quarter (readfirstlane
// -> SGPR -> scalar weight loads). 1563 blocks = 6252 waves = 6.1/SIMD (was 1.5).
// Cross-wave combine via 16KB LDS partials. y1h = raw fp16(x@W1); dinv applied in k3.
__global__ __launch_bounds__(256) void k1_hist_gemm(const int* __restrict__ ei,
                                                    const float* __restrict__ x,
                                                    const float* __restrict__ W1,
                                                    int* __restrict__ hist_blk,
                                                    __half* __restrict__ y1h) {
    __shared__ float4 part[4 * 64 * 4];  // [wave][node][quad] = 16 KB; aliased by hist
    int* h = (int*)part;
    int blk = blockIdx.x, t = threadIdx.x;

    // ---- hist phase (blocks < NBLK only) ----
    if (blk < NBLK) {
        for (int i = t; i < NB2; i += 256) h[i] = 0;
        __syncthreads();
        int e0 = blk * CHUNK;
        int eN = min(CHUNK, N_EDGES - e0);           // always %4 == 0
        const int4* d4 = (const int4*)(ei + N_EDGES + e0);
        for (int i = t; i < (eN >> 2); i += 256) {
            int4 d = d4[i];
            atomicAdd(&h[d.x >> B2SHIFT], 1);
            atomicAdd(&h[d.y >> B2SHIFT], 1);
            atomicAdd(&h[d.z >> B2SHIFT], 1);
            atomicAdd(&h[d.w >> B2SHIFT], 1);
        }
        __syncthreads();
        for (int i = t; i < NB2; i += 256) hist_blk[i * NBLK + blk] = h[i];  // bucket-major
        __syncthreads();                              // h dead before part overwrite
    }

    // ---- gemm phase: node = blk*64 + (t&63); wave (t>>6) owns K-quarter ----
    int nl = t & 63;
    int n  = blk * 64 + nl;
    int wv = __builtin_amdgcn_readfirstlane(t >> 6);  // 0..3 in SGPR -> scalar W1 path
    int nc = min(n, N_NODES - 1);                     // safe dummy row for OOB lanes

    const float4* xr = (const float4*)(x + (size_t)nc * F_IN) + wv * 16;
    const float*  w  = W1 + wv * 64 * HID;            // scalar base (SGPR)

    float acc[HID];
    #pragma unroll
    for (int j = 0; j < HID; j++) acc[j] = 0.f;

    #pragma unroll 4
    for (int k4 = 0; k4 < 16; k4++) {                 // 16 float4 = this wave's 64 features
        float4 xv = xr[k4];
        #pragma unroll
        for (int kk = 0; kk < 4; kk++) {
            const float xs = COMP(xv, kk);
            const float* wr = w + (k4 * 4 + kk) * HID;   // scalar + compile-time offsets
            #pragma unroll
            for (int hh = 0; hh < HID; hh++) acc[hh] += xs * wr[hh];
        }
    }
    // deposit partials: part[wv][nl][0..3] (2-way bank alias only)
    float4* pw = &part[(wv * 64 + nl) * 4];
    pw[0] = make_float4(acc[ 0], acc[ 1], acc[ 2], acc[ 3]);
    pw[1] = make_float4(acc[ 4], acc[ 5], acc[ 6], acc[ 7]);
    pw[2] = make_float4(acc[ 8], acc[ 9], acc[10], acc[11]);
    pw[3] = make_float4(acc[12], acc[13], acc[14], acc[15]);
    __syncthreads();

    // reduce: thread t -> (node t>>2, quad t&3); contiguous b128 reads, coalesced 8B store
    int rn = t >> 2, q = t & 3;
    float4 s0 = part[(0 * 64 + rn) * 4 + q];
    float4 s1 = part[(1 * 64 + rn) * 4 + q];
    float4 s2 = part[(2 * 64 + rn) * 4 + q];
    float4 s3 = part[(3 * 64 + rn) * 4 + q];
    float4 s = make_float4(s0.x + s1.x + s2.x + s3.x,
                           s0.y + s1.y + s2.y + s3.y,
                           s0.z + s1.z + s2.z + s3.z,
                           s0.w + s1.w + s2.w + s3.w);
    int gn = blk * 64 + rn;
    if (gn < N_NODES) {
        float2 r;
        ((__half2*)&r)[0] = __float22half2_rn(make_float2(s.x, s.y));
        ((__half2*)&r)[1] = __float22half2_rn(make_float2(s.z, s.w));
        *(float2*)(y1h + (size_t)gn * HID + q * 4) = r;
    }
}

// ---- K2: scatter edges into disjoint sub-ranges; per-bucket prefix recomputed in-block ----
// pack: (dst & 511) << 17 | src   (src < 2^17)
__global__ __launch_bounds__(512) void k2_bin(const int* __restrict__ ei,
                                              const int* __restrict__ hist_blk,
                                              int* __restrict__ buf) {
    __shared__ int cur[NB2];
    __shared__ int sc[256];
    int blk = blockIdx.x, t = threadIdx.x;
    int pre = 0, tot = 0;
    if (t < NB2) {
        const int* row = hist_blk + t * NBLK;
        for (int k = 0; k < NBLK; k++) {
            int v = row[k];
            pre += (k < blk) ? v : 0;
            tot += v;
        }
    }
    if (t < 256) sc[t] = tot;
    __syncthreads();
    for (int off = 1; off < 256; off <<= 1) {
        int u = 0;
        if (t < 256 && t >= off) u = sc[t - off];
        __syncthreads();
        if (t < 256) sc[t] += u;
        __syncthreads();
    }
    if (t < NB2) cur[t] = (sc[t] - tot) + pre;       // bucket_base + this block's prefix
    __syncthreads();

    int e0 = blk * CHUNK;
    int eN = min(CHUNK, N_EDGES - e0);               // always %4 == 0
    const int4* s4 = (const int4*)(ei + e0);
    const int4* d4 = (const int4*)(ei + N_EDGES + e0);
    for (int i = t; i < (eN >> 2); i += 512) {
        int4 d = d4[i], s = s4[i];
        int p0 = atomicAdd(&cur[d.x >> B2SHIFT], 1); buf[p0] = ((d.x & 511) << 17) | s.x;
        int p1 = atomicAdd(&cur[d.y >> B2SHIFT], 1); buf[p1] = ((d.y & 511) << 17) | s.y;
        int p2 = atomicAdd(&cur[d.z >> B2SHIFT], 1); buf[p2] = ((d.z & 511) << 17) | s.z;
        int p3 = atomicAdd(&cur[d.w >> B2SHIFT], 1); buf[p3] = ((d.w & 511) << 17) | s.w;
    }
}

// ---- K3: per-bucket fine build -> rowptr, dinv, csr_src; ALSO scales y1h row by dinv ----
// (fusing the y1h *= dinv[n] rescale here keeps gather1's edge loop free of dinv[src] loads)
__global__ __launch_bounds__(512) void k3_build(const int* __restrict__ buf,
                                               const int* __restrict__ hist_blk,
                                               int* __restrict__ rowptr,
                                               float* __restrict__ dinv,
                                               int* __restrict__ csr_src,
                                               __half* __restrict__ y1h) {
    __shared__ int lbuf[BCAP];
    __shared__ int hist[512], offs[512], cur[512];
    __shared__ int sc[256];
    __shared__ int s_base, s_cnt;
    int b = blockIdx.x, t = threadIdx.x;

    int tot = 0;
    if (t < NB2) {
        const int* row = hist_blk + t * NBLK;
        for (int k = 0; k < NBLK; k++) tot += row[k];
    }
    if (t < 256) sc[t] = tot;
    hist[t] = 0;
    __syncthreads();
    for (int off = 1; off < 256; off <<= 1) {
        int u = 0;
        if (t < 256 && t >= off) u = sc[t - off];
        __syncthreads();
        if (t < 256) sc[t] += u;
        __syncthreads();
    }
    if (t == b) { s_base = sc[b] - tot; s_cnt = tot; }
    __syncthreads();
    int base = s_base, cnt = s_cnt;

    for (int i = t; i < cnt; i += 512) {
        int v = buf[base + i];
        if (i < BCAP) lbuf[i] = v;
        atomicAdd(&hist[v >> 17], 1);
    }
    __syncthreads();
    int v = hist[t];
    offs[t] = v;
    __syncthreads();
    for (int off = 1; off < 512; off <<= 1) {
        int u = (t >= off) ? offs[t - off] : 0;
        __syncthreads();
        offs[t] += u;
        __syncthreads();
    }
    int ex = offs[t] - v;   // exclusive scan
    int n = (b << B2SHIFT) + t;
    if (n < N_NODES) {
        rowptr[n] = base + ex;
        float dv = rsqrtf((float)(v + 1));  // +1 self-loop
        dinv[n] = dv;
        // in-place rescale of this node's y1h row (row owned exclusively by this thread)
        float4* yr = (float4*)(y1h + (size_t)n * HID);
        float4 a = yr[0], bq = yr[1];
        __half2* ah = (__half2*)&a;
        __half2* bh = (__half2*)&bq;
        #pragma unroll
        for (int j = 0; j < 4; j++) {
            float2 fa = __half22float2(ah[j]);
            float2 fb = __half22float2(bh[j]);
            ah[j] = __float22half2_rn(make_float2(fa.x * dv, fa.y * dv));
            bh[j] = __float22half2_rn(make_float2(fb.x * dv, fb.y * dv));
        }
        yr[0] = a;
        yr[1] = bq;
    }
    if (b == 0 && t == 0) rowptr[N_NODES] = N_EDGES;
    cur[t] = ex;
    __syncthreads();
    for (int i = t; i < cnt; i += 512) {
        int p = (i < BCAP) ? lbuf[i] : buf[base + i];
        int pos = atomicAdd(&cur[p >> 17], 1);        // LDS atomic
        csr_src[base + pos] = p & 0x1FFFF;
    }
}

// ---- helper: accumulate one fp16 row (16 halfs as 2 float4) into acc[16] ----
__device__ __forceinline__ void acc_row(const float4* __restrict__ tab, int s, float* acc) {
    float4 v0 = tab[(size_t)s * 2 + 0];
    float4 v1 = tab[(size_t)s * 2 + 1];
    const __half2* a0 = (const __half2*)&v0;
    const __half2* a1 = (const __half2*)&v1;
    #pragma unroll
    for (int j = 0; j < 4; j++) {
        float2 f0 = __half22float2(a0[j]);
        float2 f1 = __half22float2(a1[j]);
        acc[2 * j]         += f0.x;
        acc[2 * j + 1]     += f0.y;
        acc[8 + 2 * j]     += f1.x;
        acc[8 + 2 * j + 1] += f1.y;
    }
}

// ---- helper: two fp16 rows with all 4 row-loads in flight ----
__device__ __forceinline__ void acc_row2(const float4* __restrict__ tab, int s0, int s1, float* acc) {
    float4 v0 = tab[(size_t)s0 * 2 + 0];
    float4 v1 = tab[(size_t)s0 * 2 + 1];
    float4 v2 = tab[(size_t)s1 * 2 + 0];
    float4 v3 = tab[(size_t)s1 * 2 + 1];
    const __half2* a0 = (const __half2*)&v0;
    const __half2* a1 = (const __half2*)&v1;
    const __half2* b0 = (const __half2*)&v2;
    const __half2* b1 = (const __half2*)&v3;
    #pragma unroll
    for (int j = 0; j < 4; j++) {
        float2 f0 = __half22float2(a0[j]);
        float2 f1 = __half22float2(a1[j]);
        float2 g0 = __half22float2(b0[j]);
        float2 g1 = __half22float2(b1[j]);
        acc[2 * j]         += f0.x + g0.x;
        acc[2 * j + 1]     += f0.y + g0.y;
        acc[8 + 2 * j]     += f1.x + g1.x;
        acc[8 + 2 * j + 1] += f1.y + g1.y;
    }
}

// ---- gather 1 (4 lanes/node): zh = fp16( dinv_n * relu(dinv_n * agg + b1) ) ----
// y1h rows pre-scaled by dinv[src] in k3, so the edge loop is pure row-sums.
__global__ __launch_bounds__(256) void gather1_kernel(const int* __restrict__ rowptr,
                                                      const int* __restrict__ csr_src,
                                                      const __half* __restrict__ y1h,
                                                      const float* __restrict__ b1,
                                                      const float* __restrict__ dinv,
                                                      __half* __restrict__ zh) {
    int n   = blockIdx.x * 64 + (threadIdx.x >> 2);
    int sub = threadIdx.x & 3;
    if (n >= N_NODES) return;
    const float4* tab = (const float4*)y1h;
    int beg = rowptr[n], end = rowptr[n + 1];
    float acc[16];
    #pragma unroll
    for (int i = 0; i < 16; i++) acc[i] = 0.f;
    if (sub == 0) acc_row(tab, n, acc);               // self-loop (row pre-scaled by dinv_n)
    int e = beg + sub;
    for (; e + 4 < end; e += 8)
        acc_row2(tab, csr_src[e], csr_src[e + 4], acc);
    if (e < end) acc_row(tab, csr_src[e], acc);
    #pragma unroll
    for (int m = 1; m < 4; m <<= 1) {
        #pragma unroll
        for (int i = 0; i < 16; i++) acc[i] += __shfl_xor(acc[i], m, 4);
    }
    if (sub < 2) {
        float dvn = dinv[n];
        const float4* b1q = (const float4*)b1;
        float4 ba = b1q[sub * 2], bb = b1q[sub * 2 + 1];
        float bv[8] = {ba.x, ba.y, ba.z, ba.w, bb.x, bb.y, bb.z, bb.w};
        __half2 outp[4];
        #pragma unroll
        for (int j = 0; j < 4; j++) {
            float2 r;
            r.x = fmaxf(dvn * acc[sub * 8 + 2 * j]     + bv[2 * j],     0.f) * dvn;
            r.y = fmaxf(dvn * acc[sub * 8 + 2 * j + 1] + bv[2 * j + 1], 0.f) * dvn;
            outp[j] = __float22half2_rn(r);
        }
        *(float4*)(zh + (size_t)n * HID + sub * 8) = *(float4*)outp;
    }
}

// ---- gather 2 + output GEMM fused: out[n,c] = dinv_n*(agg@W2)[c] + b2[c] ----
__global__ __launch_bounds__(256) void gather2_kernel(const int* __restrict__ rowptr,
                                                      const int* __restrict__ csr_src,
                                                      const __half* __restrict__ zh,
                                                      const float* __restrict__ W2,
                                                      const float* __restrict__ b2,
                                                      const float* __restrict__ dinv,
                                                      float* __restrict__ out) {
    __shared__ float W2s[HID * NCLS];   // 640 floats
    __shared__ float b2s[NCLS];
    int t = threadIdx.x;
    for (int i = t; i < HID * NCLS; i += 256) W2s[i] = W2[i];
    if (t < NCLS) b2s[t] = b2[t];
    __syncthreads();

    int n   = blockIdx.x * 64 + (t >> 2);
    int sub = t & 3;
    if (n >= N_NODES) return;
    const float4* tab = (const float4*)zh;
    int beg = rowptr[n], end = rowptr[n + 1];
    float acc[16];
    #pragma unroll
    for (int i = 0; i < 16; i++) acc[i] = 0.f;
    if (sub == 0) acc_row(tab, n, acc);               // self-loop (zh pre-scaled)
    int e = beg + sub;
    for (; e + 4 < end; e += 8)
        acc_row2(tab, csr_src[e], csr_src[e + 4], acc);
    if (e < end) acc_row(tab, csr_src[e], acc);
    #pragma unroll
    for (int m = 1; m < 4; m <<= 1) {
        #pragma unroll
        for (int i = 0; i < 16; i++) acc[i] += __shfl_xor(acc[i], m, 4);
    }
    // each lane computes 10 contiguous classes
    float dv = dinv[n];
    int c0 = sub * 10;
    float o[10];
    #pragma unroll
    for (int j = 0; j < 10; j++) o[j] = 0.f;
    #pragma unroll
    for (int h = 0; h < HID; h++) {
        float a = acc[h];
        const float* w = &W2s[h * NCLS + c0];
        #pragma unroll
        for (int j = 0; j < 10; j++) o[j] += a * w[j];
    }
    float* op = out + (size_t)n * NCLS + c0;
    #pragma unroll
    for (int j = 0; j < 5; j++) {
        float2 r = make_float2(dv * o[2 * j]     + b2s[c0 + 2 * j],
                               dv * o[2 * j + 1] + b2s[c0 + 2 * j + 1]);
        *(float2*)(op + 2 * j) = r;
    }
}

extern "C" void kernel_launch(void* const* d_in, const int* in_sizes, int n_in,
                              void* d_out, int out_size, void* d_ws, size_t ws_size,
                              hipStream_t stream) {
    const float* x   = (const float*)d_in[0];
    const int*   ei  = (const int*)  d_in[1];   // [2, E] int32
    const float* W1  = (const float*)d_in[2];
    const float* b1  = (const float*)d_in[3];
    const float* W2  = (const float*)d_in[4];
    const float* b2  = (const float*)d_in[5];
    float* out = (float*)d_out;

    char* ws = (char*)d_ws;
    size_t off = 0;
    int*   hist_blk = (int*)(ws + off); off += (size_t)NB2 * NBLK * 4;       // 154 KB
    off = (off + 15) & ~(size_t)15;
    int*    rowptr  = (int*)   (ws + off); off += (size_t)(N_NODES + 1) * 4;
    off = (off + 15) & ~(size_t)15;
    float*  dinv    = (float*) (ws + off); off += (size_t)N_NODES * 4;
    int*    csr_src = (int*)   (ws + off); off += (size_t)N_EDGES * 4;          // 12.8 MB
    int*    buf     = (int*)   (ws + off); off += (size_t)N_EDGES * 4;          // 12.8 MB
    __half* y1h     = (__half*)(ws + off); off += (size_t)N_NODES * HID * 2;    //  3.2 MB
    __half* zh      = (__half*)(ws + off); off += (size_t)N_NODES * HID * 2;    //  3.2 MB

    k1_hist_gemm <<<G1BLKS, 256, 0, stream>>>(ei, x, W1, hist_blk, y1h);
    k2_bin       <<<NBLK, 512, 0, stream>>>(ei, hist_blk, buf);
    k3_build     <<<NB2, 512, 0, stream>>>(buf, hist_blk, rowptr, dinv, csr_src, y1h);
    gather1_kernel<<<(N_NODES + 63) / 64, 256, 0, stream>>>(rowptr, csr_src, y1h, b1, dinv, zh);
    gather2_kernel<<<(N_NODES + 63) / 64, 256, 0, stream>>>(rowptr, csr_src, zh, W2, b2, dinv, out);
}

// Round 11
// 316.487 us; speedup vs baseline: 1.0458x; 1.0029x over previous
//
#include <hip/hip_runtime.h>
#include <hip/hip_fp16.h>

#define N_NODES   100000
#define N_EDGES   3200000
#define F_IN      256
#define HID       16
#define NCLS      40

#define CHUNK     8192
#define NCHK      ((N_EDGES + CHUNK - 1) / CHUNK)    // 391 edge chunks (last = 5120)
#define B2SHIFT   8                                  // 256 nodes per bucket
#define NB2       ((N_NODES + 255) >> B2SHIFT)       // 391 buckets
#define BCAP      9216                               // bucket cap (mean 8192, +11 sigma)
#define G1BLKS    ((N_NODES + 63) / 64)              // 1563 blocks for split-K gemm

#define COMP(v, kk) ((kk) == 0 ? (v).x : (kk) == 1 ? (v).y : (kk) == 2 ? (v).z : (v).w)

// ---- K1: pure split-K layer-1 GEMM (hist machinery deleted -> uniform blocks) ----
// 64 nodes/block x 4 waves, each wave owns one K-quarter (readfirstlane -> SGPR ->
// scalar weight loads). 1563 blocks = 6252 waves = 6.1/SIMD. LDS combine 16KB.
// y1h = raw fp16(x@W1); dinv scaling applied in k3 (when dinv exists).
__global__ __launch_bounds__(256) void k1_gemm(const float* __restrict__ x,
                                               const float* __restrict__ W1,
                                               __half* __restrict__ y1h) {
    __shared__ float4 part[4 * 64 * 4];  // [wave][node][quad] = 16 KB
    int blk = blockIdx.x, t = threadIdx.x;

    int nl = t & 63;
    int n  = blk * 64 + nl;
    int wv = __builtin_amdgcn_readfirstlane(t >> 6);  // 0..3 in SGPR -> scalar W1 path
    int nc = min(n, N_NODES - 1);                     // safe dummy row for OOB lanes

    const float4* xr = (const float4*)(x + (size_t)nc * F_IN) + wv * 16;
    const float*  w  = W1 + wv * 64 * HID;            // scalar base (SGPR)

    float acc[HID];
    #pragma unroll
    for (int j = 0; j < HID; j++) acc[j] = 0.f;

    #pragma unroll 4
    for (int k4 = 0; k4 < 16; k4++) {                 // 16 float4 = this wave's 64 features
        float4 xv = xr[k4];
        #pragma unroll
        for (int kk = 0; kk < 4; kk++) {
            const float xs = COMP(xv, kk);
            const float* wr = w + (k4 * 4 + kk) * HID;   // scalar + compile-time offsets
            #pragma unroll
            for (int hh = 0; hh < HID; hh++) acc[hh] += xs * wr[hh];
        }
    }
    float4* pw = &part[(wv * 64 + nl) * 4];
    pw[0] = make_float4(acc[ 0], acc[ 1], acc[ 2], acc[ 3]);
    pw[1] = make_float4(acc[ 4], acc[ 5], acc[ 6], acc[ 7]);
    pw[2] = make_float4(acc[ 8], acc[ 9], acc[10], acc[11]);
    pw[3] = make_float4(acc[12], acc[13], acc[14], acc[15]);
    __syncthreads();

    int rn = t >> 2, q = t & 3;
    float4 s0 = part[(0 * 64 + rn) * 4 + q];
    float4 s1 = part[(1 * 64 + rn) * 4 + q];
    float4 s2 = part[(2 * 64 + rn) * 4 + q];
    float4 s3 = part[(3 * 64 + rn) * 4 + q];
    float4 s = make_float4(s0.x + s1.x + s2.x + s3.x,
                           s0.y + s1.y + s2.y + s3.y,
                           s0.z + s1.z + s2.z + s3.z,
                           s0.w + s1.w + s2.w + s3.w);
    int gn = blk * 64 + rn;
    if (gn < N_NODES) {
        float2 r;
        ((__half2*)&r)[0] = __float22half2_rn(make_float2(s.x, s.y));
        ((__half2*)&r)[1] = __float22half2_rn(make_float2(s.z, s.w));
        *(float2*)(y1h + (size_t)gn * HID + q * 4) = r;
    }
}

// ---- K2: per-chunk LDS hist -> gcnt claim -> scatter into fixed-stride buckets ----
// Dynamic allocation: one atomicAdd(&gcnt[j], h[j]) per (block,bucket) = 77k low-
// contention atomics total (NOT per-edge -- r6's mistake). Within-bucket edge order is
// schedule-dependent -> only reorders fp32 adds downstream (~1e-6 << 9.8e-4 tol).
// 391 blocks x 512 thr = 3128 waves (~3/SIMD). pack: (dst & 255) << 17 | src.
__global__ __launch_bounds__(512) void k2_bin(const int* __restrict__ ei,
                                              int* __restrict__ gcnt,
                                              int* __restrict__ buf) {
    __shared__ int h[NB2], cur[NB2];
    int blk = blockIdx.x, t = threadIdx.x;
    for (int j = t; j < NB2; j += 512) h[j] = 0;
    __syncthreads();
    int e0 = blk * CHUNK;
    int eN = min(CHUNK, N_EDGES - e0);               // always %4 == 0 (last = 5120)
    const int4* s4 = (const int4*)(ei + e0);
    const int4* d4 = (const int4*)(ei + N_EDGES + e0);
    for (int i = t; i < (eN >> 2); i += 512) {
        int4 d = d4[i];
        atomicAdd(&h[d.x >> B2SHIFT], 1);
        atomicAdd(&h[d.y >> B2SHIFT], 1);
        atomicAdd(&h[d.z >> B2SHIFT], 1);
        atomicAdd(&h[d.w >> B2SHIFT], 1);
    }
    __syncthreads();
    for (int j = t; j < NB2; j += 512)
        cur[j] = j * BCAP + atomicAdd(&gcnt[j], h[j]);   // claim contiguous sub-range
    __syncthreads();
    for (int i = t; i < (eN >> 2); i += 512) {
        int4 d = d4[i], s = s4[i];
        int p0 = atomicAdd(&cur[d.x >> B2SHIFT], 1); buf[p0] = ((d.x & 255) << 17) | s.x;
        int p1 = atomicAdd(&cur[d.y >> B2SHIFT], 1); buf[p1] = ((d.y & 255) << 17) | s.y;
        int p2 = atomicAdd(&cur[d.z >> B2SHIFT], 1); buf[p2] = ((d.z & 255) << 17) | s.z;
        int p3 = atomicAdd(&cur[d.w >> B2SHIFT], 1); buf[p3] = ((d.w & 255) << 17) | s.w;
    }
}

// ---- K3: per-bucket fine build -> rowptr, dinv, csr_src; ALSO scales y1h row by dinv ----
// 391 blocks (1.5/CU), lbuf 36KB -> ~3 blocks/CU co-resident. Bucket counts from gcnt
// (391-int in-block scan replaces the old 196x196 prefix loop).
__global__ __launch_bounds__(512) void k3_build(const int* __restrict__ buf,
                                               const int* __restrict__ gcnt,
                                               int* __restrict__ rowptr,
                                               float* __restrict__ dinv,
                                               int* __restrict__ csr_src,
                                               __half* __restrict__ y1h) {
    __shared__ int lbuf[BCAP];           // 36 KB bucket cache
    __shared__ int hist[256], offs[256], cur[256];
    __shared__ int sc[512];
    __shared__ int s_base, s_cnt;
    int b = blockIdx.x, t = threadIdx.x;

    int cntv = (t < NB2) ? gcnt[t] : 0;
    sc[t] = cntv;
    if (t < 256) hist[t] = 0;
    __syncthreads();
    for (int off = 1; off < 512; off <<= 1) {
        int u = (t >= off) ? sc[t - off] : 0;
        __syncthreads();
        sc[t] += u;
        __syncthreads();
    }
    if (t == b) { s_base = sc[b] - cntv; s_cnt = cntv; }   // compact base, count
    __syncthreads();
    int base = s_base, cnt = s_cnt;
    int src0 = b * BCAP;

    for (int i = t; i < cnt; i += 512) {
        int v = buf[src0 + i];
        lbuf[i] = v;                                   // cnt <= BCAP by construction
        atomicAdd(&hist[v >> 17], 1);
    }
    __syncthreads();
    int v = 0, ex = 0;
    if (t < 256) {
        v = hist[t];
        offs[t] = v;
    }
    __syncthreads();
    for (int off = 1; off < 256; off <<= 1) {
        int u = 0;
        if (t < 256 && t >= off) u = offs[t - off];
        __syncthreads();
        if (t < 256) offs[t] += u;
        __syncthreads();
    }
    if (t < 256) {
        ex = offs[t] - v;   // exclusive scan: node's within-bucket start
        int n = (b << B2SHIFT) + t;
        if (n < N_NODES) {
            rowptr[n] = base + ex;
            float dv = rsqrtf((float)(v + 1));  // +1 self-loop
            dinv[n] = dv;
            // in-place rescale of this node's y1h row (row owned exclusively by this thread)
            float4* yr = (float4*)(y1h + (size_t)n * HID);
            float4 a = yr[0], bq = yr[1];
            __half2* ah = (__half2*)&a;
            __half2* bh = (__half2*)&bq;
            #pragma unroll
            for (int j = 0; j < 4; j++) {
                float2 fa = __half22float2(ah[j]);
                float2 fb = __half22float2(bh[j]);
                ah[j] = __float22half2_rn(make_float2(fa.x * dv, fa.y * dv));
                bh[j] = __float22half2_rn(make_float2(fb.x * dv, fb.y * dv));
            }
            yr[0] = a;
            yr[1] = bq;
        }
        cur[t] = ex;
    }
    if (b == 0 && t == 0) rowptr[N_NODES] = N_EDGES;
    __syncthreads();
    for (int i = t; i < cnt; i += 512) {
        int p = lbuf[i];
        int pos = atomicAdd(&cur[p >> 17], 1);        // LDS atomic
        csr_src[base + pos] = p & 0x1FFFF;
    }
}

// ---- helper: accumulate one fp16 row (16 halfs as 2 float4) into acc[16] ----
__device__ __forceinline__ void acc_row(const float4* __restrict__ tab, int s, float* acc) {
    float4 v0 = tab[(size_t)s * 2 + 0];
    float4 v1 = tab[(size_t)s * 2 + 1];
    const __half2* a0 = (const __half2*)&v0;
    const __half2* a1 = (const __half2*)&v1;
    #pragma unroll
    for (int j = 0; j < 4; j++) {
        float2 f0 = __half22float2(a0[j]);
        float2 f1 = __half22float2(a1[j]);
        acc[2 * j]         += f0.x;
        acc[2 * j + 1]     += f0.y;
        acc[8 + 2 * j]     += f1.x;
        acc[8 + 2 * j + 1] += f1.y;
    }
}

// ---- helper: two fp16 rows with all 4 row-loads in flight ----
__device__ __forceinline__ void acc_row2(const float4* __restrict__ tab, int s0, int s1, float* acc) {
    float4 v0 = tab[(size_t)s0 * 2 + 0];
    float4 v1 = tab[(size_t)s0 * 2 + 1];
    float4 v2 = tab[(size_t)s1 * 2 + 0];
    float4 v3 = tab[(size_t)s1 * 2 + 1];
    const __half2* a0 = (const __half2*)&v0;
    const __half2* a1 = (const __half2*)&v1;
    const __half2* b0 = (const __half2*)&v2;
    const __half2* b1 = (const __half2*)&v3;
    #pragma unroll
    for (int j = 0; j < 4; j++) {
        float2 f0 = __half22float2(a0[j]);
        float2 f1 = __half22float2(a1[j]);
        float2 g0 = __half22float2(b0[j]);
        float2 g1 = __half22float2(b1[j]);
        acc[2 * j]         += f0.x + g0.x;
        acc[2 * j + 1]     += f0.y + g0.y;
        acc[8 + 2 * j]     += f1.x + g1.x;
        acc[8 + 2 * j + 1] += f1.y + g1.y;
    }
}

// ---- gather 1 (4 lanes/node): zh = fp16( dinv_n * relu(dinv_n * agg + b1) ) ----
// y1h rows pre-scaled by dinv[src] in k3, so the edge loop is pure row-sums.
__global__ __launch_bounds__(256) void gather1_kernel(const int* __restrict__ rowptr,
                                                      const int* __restrict__ csr_src,
                                                      const __half* __restrict__ y1h,
                                                      const float* __restrict__ b1,
                                                      const float* __restrict__ dinv,
                                                      __half* __restrict__ zh) {
    int n   = blockIdx.x * 64 + (threadIdx.x >> 2);
    int sub = threadIdx.x & 3;
    if (n >= N_NODES) return;
    const float4* tab = (const float4*)y1h;
    int beg = rowptr[n], end = rowptr[n + 1];
    float acc[16];
    #pragma unroll
    for (int i = 0; i < 16; i++) acc[i] = 0.f;
    if (sub == 0) acc_row(tab, n, acc);               // self-loop (row pre-scaled by dinv_n)
    int e = beg + sub;
    for (; e + 4 < end; e += 8)
        acc_row2(tab, csr_src[e], csr_src[e + 4], acc);
    if (e < end) acc_row(tab, csr_src[e], acc);
    #pragma unroll
    for (int m = 1; m < 4; m <<= 1) {
        #pragma unroll
        for (int i = 0; i < 16; i++) acc[i] += __shfl_xor(acc[i], m, 4);
    }
    if (sub < 2) {
        float dvn = dinv[n];
        const float4* b1q = (const float4*)b1;
        float4 ba = b1q[sub * 2], bb = b1q[sub * 2 + 1];
        float bv[8] = {ba.x, ba.y, ba.z, ba.w, bb.x, bb.y, bb.z, bb.w};
        __half2 outp[4];
        #pragma unroll
        for (int j = 0; j < 4; j++) {
            float2 r;
            r.x = fmaxf(dvn * acc[sub * 8 + 2 * j]     + bv[2 * j],     0.f) * dvn;
            r.y = fmaxf(dvn * acc[sub * 8 + 2 * j + 1] + bv[2 * j + 1], 0.f) * dvn;
            outp[j] = __float22half2_rn(r);
        }
        *(float4*)(zh + (size_t)n * HID + sub * 8) = *(float4*)outp;
    }
}

// ---- gather 2 + output GEMM fused: out[n,c] = dinv_n*(agg@W2)[c] + b2[c] ----
__global__ __launch_bounds__(256) void gather2_kernel(const int* __restrict__ rowptr,
                                                      const int* __restrict__ csr_src,
                                                      const __half* __restrict__ zh,
                                                      const float* __restrict__ W2,
                                                      const float* __restrict__ b2,
                                                      const float* __restrict__ dinv,
                                                      float* __restrict__ out) {
    __shared__ float W2s[HID * NCLS];   // 640 floats
    __shared__ float b2s[NCLS];
    int t = threadIdx.x;
    for (int i = t; i < HID * NCLS; i += 256) W2s[i] = W2[i];
    if (t < NCLS) b2s[t] = b2[t];
    __syncthreads();

    int n   = blockIdx.x * 64 + (t >> 2);
    int sub = t & 3;
    if (n >= N_NODES) return;
    const float4* tab = (const float4*)zh;
    int beg = rowptr[n], end = rowptr[n + 1];
    float acc[16];
    #pragma unroll
    for (int i = 0; i < 16; i++) acc[i] = 0.f;
    if (sub == 0) acc_row(tab, n, acc);               // self-loop (zh pre-scaled)
    int e = beg + sub;
    for (; e + 4 < end; e += 8)
        acc_row2(tab, csr_src[e], csr_src[e + 4], acc);
    if (e < end) acc_row(tab, csr_src[e], acc);
    #pragma unroll
    for (int m = 1; m < 4; m <<= 1) {
        #pragma unroll
        for (int i = 0; i < 16; i++) acc[i] += __shfl_xor(acc[i], m, 4);
    }
    // each lane computes 10 contiguous classes
    float dv = dinv[n];
    int c0 = sub * 10;
    float o[10];
    #pragma unroll
    for (int j = 0; j < 10; j++) o[j] = 0.f;
    #pragma unroll
    for (int h = 0; h < HID; h++) {
        float a = acc[h];
        const float* w = &W2s[h * NCLS + c0];
        #pragma unroll
        for (int j = 0; j < 10; j++) o[j] += a * w[j];
    }
    float* op = out + (size_t)n * NCLS + c0;
    #pragma unroll
    for (int j = 0; j < 5; j++) {
        float2 r = make_float2(dv * o[2 * j]     + b2s[c0 + 2 * j],
                               dv * o[2 * j + 1] + b2s[c0 + 2 * j + 1]);
        *(float2*)(op + 2 * j) = r;
    }
}

extern "C" void kernel_launch(void* const* d_in, const int* in_sizes, int n_in,
                              void* d_out, int out_size, void* d_ws, size_t ws_size,
                              hipStream_t stream) {
    const float* x   = (const float*)d_in[0];
    const int*   ei  = (const int*)  d_in[1];   // [2, E] int32
    const float* W1  = (const float*)d_in[2];
    const float* b1  = (const float*)d_in[3];
    const float* W2  = (const float*)d_in[4];
    const float* b2  = (const float*)d_in[5];
    float* out = (float*)d_out;

    char* ws = (char*)d_ws;
    size_t off = 0;
    int*   gcnt = (int*)(ws + off); off += (size_t)NB2 * 4;                     // 1.6 KB
    off = (off + 15) & ~(size_t)15;
    int*    rowptr  = (int*)   (ws + off); off += (size_t)(N_NODES + 1) * 4;
    off = (off + 15) & ~(size_t)15;
    float*  dinv    = (float*) (ws + off); off += (size_t)N_NODES * 4;
    int*    csr_src = (int*)   (ws + off); off += (size_t)N_EDGES * 4;          // 12.8 MB
    int*    buf     = (int*)   (ws + off); off += (size_t)NB2 * BCAP * 4;       // 14.4 MB fixed-stride
    __half* y1h     = (__half*)(ws + off); off += (size_t)N_NODES * HID * 2;    //  3.2 MB
    __half* zh      = (__half*)(ws + off); off += (size_t)N_NODES * HID * 2;    //  3.2 MB

    hipMemsetAsync(gcnt, 0, (size_t)NB2 * 4, stream);   // graph-capture-legal async op
    k1_gemm <<<G1BLKS, 256, 0, stream>>>(x, W1, y1h);
    k2_bin  <<<NCHK, 512, 0, stream>>>(ei, gcnt, buf);
    k3_build<<<NB2, 512, 0, stream>>>(buf, gcnt, rowptr, dinv, csr_src, y1h);
    gather1_kernel<<<(N_NODES + 63) / 64, 256, 0, stream>>>(rowptr, csr_src, y1h, b1, dinv, zh);
    gather2_kernel<<<(N_NODES + 63) / 64, 256, 0, stream>>>(rowptr, csr_src, zh, W2, b2, dinv, out);
}